// Round 1
// baseline (296.887 us; speedup 1.0000x reference)
//
#include <hip/hip_runtime.h>
#include <math.h>

#define BN_EPS_F 1e-5f

// Generic fused  C = act( s * (A @ B^T) + t ),  s/t folded from bias+BN.
// A: M x K row-major (lda), B: N x K row-major (ldb)  -> NT GEMM.
// MODE 0: relu, MODE 1: sigmoid.
template<int BM, int BN, int BK, int TM, int TN, int MODE>
__global__ __launch_bounds__((BM/TM)*(BN/TN))
void gemm_bn_act(const float* __restrict__ A, int M, int K, int lda,
                 const float* __restrict__ B, int N, int ldb,
                 const float* __restrict__ bias,
                 const float* __restrict__ gamma,
                 const float* __restrict__ beta,
                 const float* __restrict__ mean,
                 const float* __restrict__ var,
                 float* __restrict__ C, int ldc)
{
    constexpr int THREADS = (BM/TM)*(BN/TN);
    constexpr int TX = BN/TN;          // threads along N
    constexpr int PAD = 4;             // keep rows 16B-aligned, break bank conflicts
    __shared__ float As[BK][BM+PAD];
    __shared__ float Bs[BK][BN+PAD];

    const int tid = threadIdx.x;
    const int tx = tid % TX;
    const int ty = tid / TX;
    const int m0 = blockIdx.y * BM;
    const int n0 = blockIdx.x * BN;

    float acc[TM][TN];
#pragma unroll
    for (int i = 0; i < TM; ++i)
#pragma unroll
        for (int j = 0; j < TN; ++j) acc[i][j] = 0.f;

    constexpr int KQ4 = BK/4;                      // float4 chunks per row of a tile
    constexpr int CA = (BM*BK)/(4*THREADS);        // float4 loads per thread (A)
    constexpr int CB = (BN*BK)/(4*THREADS);        // float4 loads per thread (B)

    const int nkt = (K + BK - 1) / BK;
    for (int t = 0; t < nkt; ++t) {
        const int kt = t * BK;
        // ---- stage A tile (BM x BK), transposed into As[k][m] ----
#pragma unroll
        for (int i = 0; i < CA; ++i) {
            int slot = tid + i*THREADS;
            int row = slot / KQ4;
            int kq  = slot % KQ4;
            int kg  = kt + 4*kq;
            float4 v = make_float4(0.f,0.f,0.f,0.f);
            if (kg + 3 < K)   // K % 4 == 0 for all layers (1000, 8) -> all-or-nothing
                v = *(const float4*)(A + (size_t)(m0+row)*lda + kg);
            As[4*kq+0][row] = v.x;
            As[4*kq+1][row] = v.y;
            As[4*kq+2][row] = v.z;
            As[4*kq+3][row] = v.w;
        }
        // ---- stage B tile (BN x BK), transposed into Bs[k][n] ----
#pragma unroll
        for (int i = 0; i < CB; ++i) {
            int slot = tid + i*THREADS;
            int row = slot / KQ4;
            int kq  = slot % KQ4;
            int kg  = kt + 4*kq;
            float4 v = make_float4(0.f,0.f,0.f,0.f);
            if (kg + 3 < K && (n0+row) < N)
                v = *(const float4*)(B + (size_t)(n0+row)*ldb + kg);
            Bs[4*kq+0][row] = v.x;
            Bs[4*kq+1][row] = v.y;
            Bs[4*kq+2][row] = v.z;
            Bs[4*kq+3][row] = v.w;
        }
        __syncthreads();
        // ---- FMA inner loop ----
#pragma unroll
        for (int kk = 0; kk < BK; ++kk) {
            float a[TM];
#pragma unroll
            for (int i = 0; i < TM; i += 4)
                *(float4*)&a[i] = *(const float4*)&As[kk][ty*TM + i];
            float bb[TN];
#pragma unroll
            for (int j = 0; j < TN; ++j) bb[j] = Bs[kk][tx + j*TX];
#pragma unroll
            for (int i = 0; i < TM; ++i)
#pragma unroll
                for (int j = 0; j < TN; ++j)
                    acc[i][j] = fmaf(a[i], bb[j], acc[i][j]);
        }
        __syncthreads();
    }

    // ---- epilogue: folded BN + activation, scalar coalesced stores ----
#pragma unroll
    for (int j = 0; j < TN; ++j) {
        const int n = n0 + tx + j*TX;
        if (n < N) {
            const float s  = gamma[n] * rsqrtf(var[n] + BN_EPS_F);
            const float t0 = fmaf(s, bias[n] - mean[n], beta[n]);
#pragma unroll
            for (int i = 0; i < TM; ++i) {
                const int m = m0 + ty*TM + i;
                float y = fmaf(s, acc[i][j], t0);
                if (MODE == 0) y = fmaxf(y, 0.f);
                else           y = 1.f / (1.f + expf(-y));
                C[(size_t)m*ldc + n] = y;
            }
        }
    }
}

// One block per batch row: 100 oscillator params staged in LDS, 300 spectral
// points computed by 300 threads (block = 320 = 5 waves).
__global__ __launch_bounds__(320)
void lorentz_kernel(const float* __restrict__ P,     // 2048 x 301 (sigmoid out)
                    const float* __restrict__ G,     // 2048 x 8
                    const float* __restrict__ wgrid, // 300
                    float* __restrict__ T)           // 2048 x 300
{
    __shared__ float s_w02[100], s_wp2[100], s_wp2g[100], s_g2[100];
    const int b   = blockIdx.x;
    const int tid = threadIdx.x;
    if (tid < 100) {
        const float* p = P + (size_t)b*301 + 3*tid;
        const float w0 = p[0]*5.f;
        const float wp = p[1]*5.f;
        const float g  = p[2]*0.5f;
        s_w02[tid]  = w0*w0;
        s_wp2[tid]  = wp*wp;
        s_g2[tid]   = g*g;
        s_wp2g[tid] = wp*wp*g;
    }
    __syncthreads();
    if (tid < 300) {
        const float wg = wgrid[tid];
        const float w2 = wg*wg;
        float e1 = 0.f, e2s = 0.f;
#pragma unroll 10
        for (int l = 0; l < 100; ++l) {
            const float s1    = s_w02[l] - w2;
            const float denom = fmaf(s1, s1, w2 * s_g2[l]);
            const float r     = __builtin_amdgcn_rcpf(denom);  // ~1 ulp, fine vs 7.7e-3 tol
            e1  = fmaf(s_wp2[l]*s1, r, e1);
            e2s = fmaf(s_wp2g[l],   r, e2s);
        }
        e1 += 10.f;
        const float e2  = e2s * wg;
        const float mag = sqrtf(fmaf(e1, e1, e2*e2));
        const float nn  = sqrtf(0.5f*(mag + e1));
        const float kk  = sqrtf(fmaxf(0.5f*(mag - e1), 0.f));
        const float d   = fmaxf(fmaxf(G[b*8+4], G[b*8+5]),
                                fmaxf(G[b*8+6], G[b*8+7]));
        const float ab  = expf(-0.006283185307179586f * d * kk); // -0.0005*4*pi
        const float np1 = nn + 1.f;
        const float Tv  = 4.f*nn / fmaf(np1, np1, kk*kk) * ab;
        T[(size_t)b*300 + tid] = Tv;
    }
}

extern "C" void kernel_launch(void* const* d_in, const int* in_sizes, int n_in,
                              void* d_out, int out_size, void* d_ws, size_t ws_size,
                              hipStream_t stream) {
    const float* G      = (const float*)d_in[0];
    const float* W1     = (const float*)d_in[1];
    const float* b1     = (const float*)d_in[2];
    const float* gamma1 = (const float*)d_in[3];
    const float* beta1  = (const float*)d_in[4];
    const float* mean1  = (const float*)d_in[5];
    const float* var1   = (const float*)d_in[6];
    const float* W2     = (const float*)d_in[7];
    const float* b2     = (const float*)d_in[8];
    const float* gamma2 = (const float*)d_in[9];
    const float* beta2  = (const float*)d_in[10];
    const float* mean2  = (const float*)d_in[11];
    const float* var2   = (const float*)d_in[12];
    const float* W3     = (const float*)d_in[13];
    const float* b3     = (const float*)d_in[14];
    const float* gamma3 = (const float*)d_in[15];
    const float* beta3  = (const float*)d_in[16];
    const float* mean3  = (const float*)d_in[17];
    const float* var3   = (const float*)d_in[18];
    const float* wgrid  = (const float*)d_in[19];

    float* ws = (float*)d_ws;
    float* h1 = ws;                       // 2048*1000
    float* h2 = ws + 2048*1000;           // 2048*1000
    float* p  = ws + 2*2048*1000;         // 2048*301
    float* T  = (float*)d_out;

    // Layer 1: 2048x1000, K=8
    gemm_bn_act<64,64,16,8,4,0><<<dim3(16,32), 128, 0, stream>>>(
        G, 2048, 8, 8, W1, 1000, 8, b1, gamma1, beta1, mean1, var1, h1, 1000);
    // Layer 2: 2048x1000, K=1000  (dominant GEMM)
    gemm_bn_act<64,64,16,8,4,0><<<dim3(16,32), 128, 0, stream>>>(
        h1, 2048, 1000, 1000, W2, 1000, 1000, b2, gamma2, beta2, mean2, var2, h2, 1000);
    // Layer 3: 2048x301, K=1000, sigmoid
    gemm_bn_act<32,64,16,4,4,1><<<dim3(5,64), 128, 0, stream>>>(
        h2, 2048, 1000, 1000, W3, 301, 1000, b3, gamma3, beta3, mean3, var3, p, 301);
    // Lorentz spectrum
    lorentz_kernel<<<2048, 320, 0, stream>>>(p, G, wgrid, T);
}